// Round 1
// baseline (174.268 us; speedup 1.0000x reference)
//
#include <hip/hip_runtime.h>
#include <stdint.h>

#define IN_C 128
#define HC 128
#define HEADS 4
#define NEG_SLOPE 0.2f
#define TB 32    // nodes per block in projection kernel
#define NPB 4    // nodes per block in aggregation kernel

// float -> bf16 bits, round-to-nearest-even
static __device__ __forceinline__ unsigned short f2b(float f) {
    unsigned int u = __float_as_uint(f);
    unsigned int r = (u + 0x7fffu + ((u >> 16) & 1u)) >> 16;
    return (unsigned short)r;
}

// Kernel A: xp = x @ lin_w (bf16 out), plus per-node per-head logit dots
// a_src[n,h] = sum_c xp[n,h*32+c]*att[h*32+c], a_dst likewise with att[128+...]
__global__ __launch_bounds__(256) void gat_proj_kernel(
    const float* __restrict__ x, const float* __restrict__ lin_w,
    const float* __restrict__ att, unsigned short* __restrict__ xp,
    float* __restrict__ a_src, float* __restrict__ a_dst, int n) {
    __shared__ float w_lds[64 * HC];    // 32 KB (half of lin_w at a time)
    __shared__ float x_lds[TB][IN_C];   // 16 KB
    const int t = threadIdx.x;
    const int node0 = blockIdx.x * TB;

    // stage x tile
    {
        const float4* src4 = (const float4*)(x + (size_t)node0 * IN_C);
        float4* dst4 = (float4*)x_lds;
        for (int i = t; i < TB * IN_C / 4; i += 256) {
            int row = i >> 5;  // 32 float4 per row
            dst4[i] = (node0 + row < n) ? src4[i] : make_float4(0.f, 0.f, 0.f, 0.f);
        }
    }

    const int cg = t & 31;   // col group -> cols c0..c0+3
    const int rg = t >> 5;   // row group -> rows r0..r0+3
    const int c0 = cg * 4;
    const int r0 = rg * 4;

    float acc[4][4];
#pragma unroll
    for (int r = 0; r < 4; r++)
#pragma unroll
        for (int j = 0; j < 4; j++) acc[r][j] = 0.f;

    for (int half = 0; half < 2; half++) {
        __syncthreads();  // x visible (half 0) / w reads of prev half done (half 1)
        {
            const float4* wsrc = (const float4*)(lin_w + (size_t)half * 64 * HC);
            float4* wl4 = (float4*)w_lds;
            for (int i = t; i < 64 * HC / 4; i += 256) wl4[i] = wsrc[i];
        }
        __syncthreads();
        const int kbase = half * 64;
        for (int k = 0; k < 64; k += 4) {
            float4 xv[4];
#pragma unroll
            for (int r = 0; r < 4; r++)
                xv[r] = *(const float4*)&x_lds[r0 + r][kbase + k];
#pragma unroll
            for (int kk = 0; kk < 4; kk++) {
                float4 wv = *(const float4*)&w_lds[(k + kk) * HC + c0];
#pragma unroll
                for (int r = 0; r < 4; r++) {
                    float xs = ((const float*)&xv[r])[kk];
                    acc[r][0] = fmaf(xs, wv.x, acc[r][0]);
                    acc[r][1] = fmaf(xs, wv.y, acc[r][1]);
                    acc[r][2] = fmaf(xs, wv.z, acc[r][2]);
                    acc[r][3] = fmaf(xs, wv.w, acc[r][3]);
                }
            }
        }
    }

    // epilogue: logit partial dots + shuffle reduce over the 8 lanes of each head
    const float as0 = att[c0], as1 = att[c0 + 1], as2 = att[c0 + 2], as3 = att[c0 + 3];
    const float ad0 = att[HC + c0], ad1 = att[HC + c0 + 1], ad2 = att[HC + c0 + 2], ad3 = att[HC + c0 + 3];
    const int h = c0 >> 5;
#pragma unroll
    for (int r = 0; r < 4; r++) {
        const int row = node0 + r0 + r;
        float ps = acc[r][0] * as0 + acc[r][1] * as1 + acc[r][2] * as2 + acc[r][3] * as3;
        float pd = acc[r][0] * ad0 + acc[r][1] * ad1 + acc[r][2] * ad2 + acc[r][3] * ad3;
#pragma unroll
        for (int mask = 1; mask <= 4; mask <<= 1) {
            ps += __shfl_xor(ps, mask, 64);
            pd += __shfl_xor(pd, mask, 64);
        }
        if (row < n) {
            if ((cg & 7) == 0) {
                a_src[(size_t)row * HEADS + h] = ps;
                a_dst[(size_t)row * HEADS + h] = pd;
            }
            ushort4 o;
            o.x = f2b(acc[r][0]);
            o.y = f2b(acc[r][1]);
            o.z = f2b(acc[r][2]);
            o.w = f2b(acc[r][3]);
            *(ushort4*)(xp + (size_t)row * HC + c0) = o;
        }
    }
}

// Kernel C: per-dst-node 8-edge softmax + weighted aggregation.
// One 64-lane wave per node, NPB nodes per 256-thread block.
__global__ __launch_bounds__(256) void gat_aggr_kernel(
    const unsigned short* __restrict__ xp, const float* __restrict__ a_src,
    const float* __restrict__ a_dst, const int* __restrict__ row_ptr,
    const int* __restrict__ col_ind, const float* __restrict__ bias,
    float* __restrict__ out, int n) {
    __shared__ float alpha_l[NPB][32];
    __shared__ int src_l[NPB][8];
    const int t = threadIdx.x;
    const int w = t >> 6;
    const int lane = t & 63;
    const int node = blockIdx.x * NPB + w;

    int deg = 0;
    if (node < n) {
        int rs = row_ptr[node];
        int re = row_ptr[node + 1];
        deg = re - rs;
        if (deg > 8) deg = 8;
        if (lane < 8) src_l[w][lane] = (lane < deg) ? col_ind[rs + lane] : 0;
    }
    __syncthreads();

    if (node < n && lane < 32) {
        const int e = lane >> 2, h = lane & 3;
        float v = -1e30f;
        if (e < deg) {
            int s = src_l[w][e];
            float z = a_src[(size_t)s * HEADS + h] + a_dst[(size_t)node * HEADS + h];
            v = (z >= 0.f) ? z : NEG_SLOPE * z;
        }
        float m = v;
        m = fmaxf(m, __shfl_xor(m, 4, 64));
        m = fmaxf(m, __shfl_xor(m, 8, 64));
        m = fmaxf(m, __shfl_xor(m, 16, 64));
        float ex = (e < deg) ? __expf(v - m) : 0.f;
        float ssum = ex;
        ssum += __shfl_xor(ssum, 4, 64);
        ssum += __shfl_xor(ssum, 8, 64);
        ssum += __shfl_xor(ssum, 16, 64);
        alpha_l[w][lane] = ex / ssum;
    }
    __syncthreads();
    if (node >= n) return;

    const int c0 = lane * 2;
    const int h = lane >> 4;  // head of cols 2*lane, 2*lane+1
    float acc0 = 0.f, acc1 = 0.f;
    if (deg == 8) {
        unsigned int pv[8];
#pragma unroll
        for (int e = 0; e < 8; e++)
            pv[e] = *(const unsigned int*)(xp + (size_t)src_l[w][e] * HC + c0);
#pragma unroll
        for (int e = 0; e < 8; e++) {
            float a = alpha_l[w][e * 4 + h];
            acc0 = fmaf(a, __uint_as_float(pv[e] << 16), acc0);
            acc1 = fmaf(a, __uint_as_float(pv[e] & 0xffff0000u), acc1);
        }
    } else {
        for (int e = 0; e < deg; e++) {
            float a = alpha_l[w][e * 4 + h];
            unsigned int pv = *(const unsigned int*)(xp + (size_t)src_l[w][e] * HC + c0);
            acc0 = fmaf(a, __uint_as_float(pv << 16), acc0);
            acc1 = fmaf(a, __uint_as_float(pv & 0xffff0000u), acc1);
        }
    }
    float2 b2 = ((const float2*)bias)[lane];
    float2 o = make_float2(acc0 + b2.x, acc1 + b2.y);
    ((float2*)(out + (size_t)node * HC))[lane] = o;
}

extern "C" void kernel_launch(void* const* d_in, const int* in_sizes, int n_in,
                              void* d_out, int out_size, void* d_ws, size_t ws_size,
                              hipStream_t stream) {
    const float* x = (const float*)d_in[0];
    const int* row_ptr = (const int*)d_in[1];
    const int* col_ind = (const int*)d_in[2];
    // d_in[3] = max_num_neighbors (unused; row_ptr is authoritative)
    const float* lin_w = (const float*)d_in[4];
    const float* att = (const float*)d_in[5];
    const float* bias = (const float*)d_in[6];
    float* out = (float*)d_out;
    const int n = in_sizes[0] / IN_C;

    unsigned short* xp = (unsigned short*)d_ws;                       // n*128 bf16
    float* a_src = (float*)((char*)d_ws + (size_t)n * HC * 2);        // n*4 f32
    float* a_dst = a_src + (size_t)n * HEADS;                         // n*4 f32

    dim3 grid_a((n + TB - 1) / TB);
    hipLaunchKernelGGL(gat_proj_kernel, grid_a, dim3(256), 0, stream,
                       x, lin_w, att, xp, a_src, a_dst, n);
    dim3 grid_c((n + NPB - 1) / NPB);
    hipLaunchKernelGGL(gat_aggr_kernel, grid_c, dim3(256), 0, stream,
                       xp, a_src, a_dst, row_ptr, col_ind, bias, out, n);
}

// Round 2
// 81.603 us; speedup vs baseline: 2.1356x; 2.1356x over previous
//
#include <hip/hip_runtime.h>
#include <stdint.h>

#define HEADS 4
#define NEG_SLOPE 0.2f
#define NPB 4      // nodes per block in aggregation kernel
#define MB 128     // rows per block in projection kernel

typedef _Float16 f16;
typedef f16 f16x8 __attribute__((ext_vector_type(8)));
typedef f16 f16x2 __attribute__((ext_vector_type(2)));
typedef float f32x4 __attribute__((ext_vector_type(4)));

// swizzled LDS byte offset for a [rows][128] f16 tile (256 B rows):
// XOR row bits into the 16B-slot bits to kill the 16-way bank conflict
#define SWZ(row, kb) (((row) << 8) + ((kb) ^ (((row) & 7) << 4)))

// ---- pre-kernel: w (f32 [K=128][N=128]) -> wt (f16 [N=128][K=128]) ----
__global__ __launch_bounds__(256) void wt_kernel(const float* __restrict__ w,
                                                 f16* __restrict__ wt) {
    __shared__ f16 tl[16][136];  // +8 pad; row stride 272 B (16B multiple)
    const int b = blockIdx.x, t = threadIdx.x;
    for (int i = t; i < 2048; i += 256) {   // 128 k-rows x 16 cols of this slice
        int k = i >> 4, nl = i & 15;
        tl[nl][k] = (f16)w[k * 128 + b * 16 + nl];
    }
    __syncthreads();
    {
        int nl = t >> 4, kc = t & 15;       // 16 rows x 16 chunks = 256 threads
        f16x8 v = *(const f16x8*)&tl[nl][kc * 8];
        *(f16x8*)(wt + (b * 16 + nl) * 128 + kc * 8) = v;
    }
}

// ---- projection: xp = f16(x) @ f16(w) via MFMA, + logit dots a_src/a_dst ----
__global__ __launch_bounds__(256) void gat_proj_mfma(
    const float* __restrict__ x, const f16* __restrict__ wt,
    const float* __restrict__ att, f16* __restrict__ xp,
    float* __restrict__ a_src, float* __restrict__ a_dst, int n) {
    __shared__ unsigned char lds[65536];   // [0,32K) = wt swizzled; [32K,64K) = x / xp swizzled
    __shared__ float att_l[256];
    const int t = threadIdx.x;
    const int node0 = blockIdx.x * MB;
    const int lane = t & 63;
    const int wv = t >> 6;

    att_l[t] = att[t];

    // stage wt (f16, already [N][K]) into swizzled LDS
    for (int i = t; i < 2048; i += 256) {
        int row = i >> 4, kc = i & 15;
        uint4 v = *(const uint4*)(wt + row * 128 + kc * 8);
        *(uint4*)(lds + SWZ(row, kc * 16)) = v;
    }
    // stage x tile, converting f32 -> f16
    for (int i = t; i < 2048; i += 256) {
        int row = i >> 4, kc = i & 15;
        int grow = node0 + row;
        float4 a = make_float4(0.f, 0.f, 0.f, 0.f), b = a;
        if (grow < n) {
            const float4* p = (const float4*)(x + (size_t)grow * 128 + kc * 8);
            a = p[0];
            b = p[1];
        }
        f16x8 hv;
        hv[0] = (f16)a.x; hv[1] = (f16)a.y; hv[2] = (f16)a.z; hv[3] = (f16)a.w;
        hv[4] = (f16)b.x; hv[5] = (f16)b.y; hv[6] = (f16)b.z; hv[7] = (f16)b.w;
        *(f16x8*)(lds + 32768 + SWZ(row, kc * 16)) = hv;
    }
    __syncthreads();

    // MFMA main loop: wave wv owns rows wv*32 .. wv*32+31 (2 M-frags), all 128 cols
    f32x4 acc[2][8];
#pragma unroll
    for (int mi = 0; mi < 2; mi++)
#pragma unroll
        for (int nf = 0; nf < 8; nf++)
            acc[mi][nf] = (f32x4){0.f, 0.f, 0.f, 0.f};

#pragma unroll
    for (int kt = 0; kt < 4; kt++) {
        const int kb = kt * 64 + (lane >> 4) * 16;
        f16x8 afr[2];
#pragma unroll
        for (int mi = 0; mi < 2; mi++) {
            int row = wv * 32 + mi * 16 + (lane & 15);
            afr[mi] = *(const f16x8*)(lds + 32768 + SWZ(row, kb));
        }
#pragma unroll
        for (int nf = 0; nf < 8; nf++) {
            int wrow = nf * 16 + (lane & 15);
            f16x8 bfr = *(const f16x8*)(lds + SWZ(wrow, kb));
            acc[0][nf] = __builtin_amdgcn_mfma_f32_16x16x32_f16(afr[0], bfr, acc[0][nf], 0, 0, 0);
            acc[1][nf] = __builtin_amdgcn_mfma_f32_16x16x32_f16(afr[1], bfr, acc[1][nf], 0, 0, 0);
        }
    }

    // repack accumulators (f16) into the x LDS region for vectorized stores
    __syncthreads();  // everyone done reading x/wt LDS
#pragma unroll
    for (int mi = 0; mi < 2; mi++)
#pragma unroll
        for (int r = 0; r < 4; r++) {
            int row = wv * 32 + mi * 16 + (lane >> 4) * 4 + r;
#pragma unroll
            for (int nf = 0; nf < 8; nf++) {
                int col = nf * 16 + (lane & 15);
                *(f16*)(lds + 32768 + SWZ(row, col * 2)) = (f16)acc[mi][nf][r];
            }
        }
    __syncthreads();

    // logit dots: a_src[n,h] = sum_c xp[n,h*32+c]*att[h*32+c]; a_dst with att[128+..]
    for (int i = t; i < MB * HEADS; i += 256) {
        int row = i >> 2, h = i & 3;
        int grow = node0 + row;
        if (grow < n) {
            float s = 0.f, d = 0.f;
#pragma unroll
            for (int cc = 0; cc < 4; cc++) {
                f16x8 v = *(const f16x8*)(lds + 32768 + SWZ(row, h * 64 + cc * 16));
#pragma unroll
                for (int j = 0; j < 8; j++) {
                    float xv = (float)v[j];
                    int c = cc * 8 + j;
                    s = fmaf(xv, att_l[h * 32 + c], s);
                    d = fmaf(xv, att_l[128 + h * 32 + c], d);
                }
            }
            a_src[(size_t)grow * HEADS + h] = s;
            a_dst[(size_t)grow * HEADS + h] = d;
        }
    }
    // write xp tile out (vectorized 16B stores)
    for (int i = t; i < 2048; i += 256) {
        int row = i >> 4, kc = i & 15;
        int grow = node0 + row;
        if (grow < n)
            *(uint4*)(xp + (size_t)grow * 128 + kc * 8) =
                *(const uint4*)(lds + 32768 + SWZ(row, kc * 16));
    }
}

// ---- aggregation: per-dst 8-edge softmax + weighted gather-sum ----
__global__ __launch_bounds__(256) void gat_aggr_kernel(
    const f16* __restrict__ xp, const float* __restrict__ a_src,
    const float* __restrict__ a_dst, const int* __restrict__ row_ptr,
    const int* __restrict__ col_ind, const float* __restrict__ bias,
    float* __restrict__ out, int n) {
    __shared__ float alpha_l[NPB][32];
    __shared__ int src_l[NPB][8];
    const int t = threadIdx.x;
    const int w = t >> 6;
    const int lane = t & 63;
    const int node = blockIdx.x * NPB + w;

    int deg = 0;
    if (node < n) {
        int rs = row_ptr[node];
        int re = row_ptr[node + 1];
        deg = re - rs;
        if (deg > 8) deg = 8;
        if (lane < 8) src_l[w][lane] = (lane < deg) ? col_ind[rs + lane] : 0;
    }
    __syncthreads();

    if (node < n && lane < 32) {
        const int e = lane >> 2, h = lane & 3;
        float v = -1e30f;
        if (e < deg) {
            int s = src_l[w][e];
            float z = a_src[(size_t)s * HEADS + h] + a_dst[(size_t)node * HEADS + h];
            v = (z >= 0.f) ? z : NEG_SLOPE * z;
        }
        float m = v;
        m = fmaxf(m, __shfl_xor(m, 4, 64));
        m = fmaxf(m, __shfl_xor(m, 8, 64));
        m = fmaxf(m, __shfl_xor(m, 16, 64));
        float ex = (e < deg) ? __expf(v - m) : 0.f;
        float ssum = ex;
        ssum += __shfl_xor(ssum, 4, 64);
        ssum += __shfl_xor(ssum, 8, 64);
        ssum += __shfl_xor(ssum, 16, 64);
        alpha_l[w][lane] = ex / ssum;
    }
    __syncthreads();
    if (node >= n) return;

    const int c0 = lane * 2;
    const int h = lane >> 4;
    float acc0 = 0.f, acc1 = 0.f;
    if (deg == 8) {
        f16x2 pv[8];
#pragma unroll
        for (int e = 0; e < 8; e++)
            pv[e] = *(const f16x2*)(xp + (size_t)src_l[w][e] * 128 + c0);
#pragma unroll
        for (int e = 0; e < 8; e++) {
            float a = alpha_l[w][e * 4 + h];
            acc0 = fmaf(a, (float)pv[e][0], acc0);
            acc1 = fmaf(a, (float)pv[e][1], acc1);
        }
    } else {
        for (int e = 0; e < deg; e++) {
            float a = alpha_l[w][e * 4 + h];
            f16x2 pv = *(const f16x2*)(xp + (size_t)src_l[w][e] * 128 + c0);
            acc0 = fmaf(a, (float)pv[0], acc0);
            acc1 = fmaf(a, (float)pv[1], acc1);
        }
    }
    float2 b2 = ((const float2*)bias)[lane];
    ((float2*)(out + (size_t)node * 128))[lane] = make_float2(acc0 + b2.x, acc1 + b2.y);
}

extern "C" void kernel_launch(void* const* d_in, const int* in_sizes, int n_in,
                              void* d_out, int out_size, void* d_ws, size_t ws_size,
                              hipStream_t stream) {
    const float* x = (const float*)d_in[0];
    const int* row_ptr = (const int*)d_in[1];
    const int* col_ind = (const int*)d_in[2];
    // d_in[3] = max_num_neighbors (row_ptr is authoritative)
    const float* lin_w = (const float*)d_in[4];
    const float* att = (const float*)d_in[5];
    const float* bias = (const float*)d_in[6];
    float* out = (float*)d_out;
    const int n = in_sizes[0] / 128;

    f16* xp = (f16*)d_ws;                                          // n*128 f16
    float* a_src = (float*)((char*)d_ws + (size_t)n * 128 * 2);    // n*4 f32
    float* a_dst = a_src + (size_t)n * HEADS;                      // n*4 f32
    f16* wt = (f16*)(a_dst + (size_t)n * HEADS);                   // 128*128 f16

    hipLaunchKernelGGL(wt_kernel, dim3(8), dim3(256), 0, stream, lin_w, wt);
    hipLaunchKernelGGL(gat_proj_mfma, dim3((n + MB - 1) / MB), dim3(256), 0, stream,
                       x, wt, att, xp, a_src, a_dst, n);
    hipLaunchKernelGGL(gat_aggr_kernel, dim3((n + NPB - 1) / NPB), dim3(256), 0, stream,
                       xp, a_src, a_dst, row_ptr, col_ind, bias, out, n);
}

// Round 3
// 76.623 us; speedup vs baseline: 2.2744x; 1.0650x over previous
//
#include <hip/hip_runtime.h>
#include <stdint.h>

#define HEADS 4
#define NEG_SLOPE 0.2f
#define MB 64      // rows per block in projection kernel

typedef _Float16 f16;
typedef f16 f16x8 __attribute__((ext_vector_type(8)));
typedef f16 f16x4 __attribute__((ext_vector_type(4)));
typedef float f32x4 __attribute__((ext_vector_type(4)));

// swizzled LDS byte offset for a [rows][128] f16 tile (256 B rows):
// XOR row bits into the 16B-slot bits to kill the 16-way bank conflict
#define SWZ(row, kb) (((row) << 8) + ((kb) ^ (((row) & 7) << 4)))

// ---- pre-kernel: w (f32 [K=128][N=128]) -> wt (f16 [N=128][K=128]) ----
__global__ __launch_bounds__(256) void wt_kernel(const float* __restrict__ w,
                                                 f16* __restrict__ wt) {
    __shared__ f16 tl[16][136];  // +8 pad
    const int b = blockIdx.x, t = threadIdx.x;
    for (int i = t; i < 2048; i += 256) {   // 128 k-rows x 16 cols of this slice
        int k = i >> 4, nl = i & 15;
        tl[nl][k] = (f16)w[k * 128 + b * 16 + nl];
    }
    __syncthreads();
    {
        int nl = t >> 4, kc = t & 15;       // 16 rows x 16 chunks = 256 threads
        f16x8 v = *(const f16x8*)&tl[nl][kc * 8];
        *(f16x8*)(wt + (b * 16 + nl) * 128 + kc * 8) = v;
    }
}

// ---- projection: xp = f16(x) @ f16(w) via MFMA, + logit dots a_src/a_dst ----
__global__ __launch_bounds__(256) void gat_proj_mfma(
    const float* __restrict__ x, const f16* __restrict__ wt,
    const float* __restrict__ att, f16* __restrict__ xp,
    float* __restrict__ a_src, float* __restrict__ a_dst, int n) {
    __shared__ unsigned char lds[49152];   // [0,32K) = wt swizzled; [32K,48K) = x / xp swizzled
    __shared__ float att_l[256];
    const int t = threadIdx.x;
    const int node0 = blockIdx.x * MB;
    const int lane = t & 63;
    const int wv = t >> 6;

    att_l[t] = att[t];

    // stage wt (f16, already [N][K]) into swizzled LDS
    for (int i = t; i < 2048; i += 256) {
        int row = i >> 4, kc = i & 15;
        uint4 v = *(const uint4*)(wt + row * 128 + kc * 8);
        *(uint4*)(lds + SWZ(row, kc * 16)) = v;
    }
    // stage x tile (MB=64 rows), converting f32 -> f16
    for (int i = t; i < 1024; i += 256) {
        int row = i >> 4, kc = i & 15;
        int grow = node0 + row;
        float4 a = make_float4(0.f, 0.f, 0.f, 0.f), b = a;
        if (grow < n) {
            const float4* p = (const float4*)(x + (size_t)grow * 128 + kc * 8);
            a = p[0];
            b = p[1];
        }
        f16x8 hv;
        hv[0] = (f16)a.x; hv[1] = (f16)a.y; hv[2] = (f16)a.z; hv[3] = (f16)a.w;
        hv[4] = (f16)b.x; hv[5] = (f16)b.y; hv[6] = (f16)b.z; hv[7] = (f16)b.w;
        *(f16x8*)(lds + 32768 + SWZ(row, kc * 16)) = hv;
    }
    __syncthreads();

    // MFMA: wave wv owns rows wv*16 .. wv*16+15 (1 M-frag), all 128 cols
    f32x4 acc[8];
#pragma unroll
    for (int nf = 0; nf < 8; nf++) acc[nf] = (f32x4){0.f, 0.f, 0.f, 0.f};

#pragma unroll
    for (int kt = 0; kt < 4; kt++) {
        const int kb = kt * 64 + (lane >> 4) * 16;
        int arow = wv * 16 + (lane & 15);
        f16x8 afr = *(const f16x8*)(lds + 32768 + SWZ(arow, kb));
#pragma unroll
        for (int nf = 0; nf < 8; nf++) {
            int wrow = nf * 16 + (lane & 15);
            f16x8 bfr = *(const f16x8*)(lds + SWZ(wrow, kb));
            acc[nf] = __builtin_amdgcn_mfma_f32_16x16x32_f16(afr, bfr, acc[nf], 0, 0, 0);
        }
    }

    // repack accumulators (f16) into the x LDS region for vectorized stores
    __syncthreads();  // everyone done reading x LDS
#pragma unroll
    for (int r = 0; r < 4; r++) {
        int row = wv * 16 + (lane >> 4) * 4 + r;
#pragma unroll
        for (int nf = 0; nf < 8; nf++) {
            int col = nf * 16 + (lane & 15);
            *(f16*)(lds + 32768 + SWZ(row, col * 2)) = (f16)acc[nf][r];
        }
    }
    __syncthreads();

    // logit dots: a_src[n,h] = sum_c xp[n,h*32+c]*att[h*32+c]; a_dst with att[128+..]
    {
        int row = t >> 2, h = t & 3;        // 64 rows x 4 heads = 256 threads
        int grow = node0 + row;
        if (grow < n) {
            float s = 0.f, d = 0.f;
#pragma unroll
            for (int cc = 0; cc < 4; cc++) {
                f16x8 v = *(const f16x8*)(lds + 32768 + SWZ(row, h * 64 + cc * 16));
#pragma unroll
                for (int j = 0; j < 8; j++) {
                    float xv = (float)v[j];
                    int c = cc * 8 + j;
                    s = fmaf(xv, att_l[h * 32 + c], s);
                    d = fmaf(xv, att_l[128 + h * 32 + c], d);
                }
            }
            a_src[(size_t)grow * HEADS + h] = s;
            a_dst[(size_t)grow * HEADS + h] = d;
        }
    }
    // write xp tile out (vectorized 16B stores)
    for (int i = t; i < 1024; i += 256) {
        int row = i >> 4, kc = i & 15;
        int grow = node0 + row;
        if (grow < n)
            *(uint4*)(xp + (size_t)grow * 128 + kc * 8) =
                *(const uint4*)(lds + 32768 + SWZ(row, kc * 16));
    }
}

// ---- aggregation: one wave per node, barrier-free, LDS-free ----
// lanes: p=lane>>5 selects edge parity, l=lane&31 owns cols 4l..4l+3
__global__ __launch_bounds__(256) void gat_aggr_kernel(
    const f16* __restrict__ xp, const float* __restrict__ a_src,
    const float* __restrict__ a_dst, const int* __restrict__ row_ptr,
    const int* __restrict__ col_ind, const float* __restrict__ bias,
    float* __restrict__ out, int n) {
    const int lane = threadIdx.x & 63;
    const int node = blockIdx.x * 4 + (threadIdx.x >> 6);
    if (node >= n) return;

    int rs = row_ptr[node];
    int deg = row_ptr[node + 1] - rs;
    if (deg > 8) deg = 8;
    // lane e holds src of edge e&7
    int src0 = ((lane & 7) < deg) ? col_ind[rs + (lane & 7)] : 0;

    // early-issue the xp gathers: half p reads edges {p,2+p,4+p,6+p},
    // each as f16x4 (32 lanes x 8B = one 256B row per half per instr)
    const int p = lane >> 5, l = lane & 31;
    f16x4 pv[4];
#pragma unroll
    for (int k = 0; k < 4; k++) {
        int s = __shfl(src0, 2 * k + p, 64);
        pv[k] = *(const f16x4*)(xp + (size_t)s * 128 + l * 4);
    }

    // softmax over 8 edges x 4 heads, replicated in each 32-lane half
    const int ea = (lane >> 2) & 7, ha = lane & 3;
    int sa = __shfl(src0, ea, 64);
    float v = -1e30f;
    if (ea < deg) {
        float z = a_src[(size_t)sa * HEADS + ha] + a_dst[(size_t)node * HEADS + ha];
        v = (z >= 0.f) ? z : NEG_SLOPE * z;
    }
    float m = v;
    m = fmaxf(m, __shfl_xor(m, 4, 64));
    m = fmaxf(m, __shfl_xor(m, 8, 64));
    m = fmaxf(m, __shfl_xor(m, 16, 64));
    float ex = (ea < deg) ? __expf(v - m) : 0.f;
    float ss = ex;
    ss += __shfl_xor(ss, 4, 64);
    ss += __shfl_xor(ss, 8, 64);
    ss += __shfl_xor(ss, 16, 64);
    float alpha = ex * ((ss > 0.f) ? (1.f / ss) : 0.f);

    // weighted accumulate: this lane's 4 cols belong to head l>>3
    const int h = l >> 3;
    float a0 = 0.f, a1 = 0.f, a2 = 0.f, a3 = 0.f;
#pragma unroll
    for (int k = 0; k < 4; k++) {
        int e = 2 * k + p;
        float a = __shfl(alpha, e * 4 + h, 32);   // within own half
        a0 = fmaf(a, (float)pv[k][0], a0);
        a1 = fmaf(a, (float)pv[k][1], a1);
        a2 = fmaf(a, (float)pv[k][2], a2);
        a3 = fmaf(a, (float)pv[k][3], a3);
    }
    // combine the two edge-parity halves
    a0 += __shfl_xor(a0, 32, 64);
    a1 += __shfl_xor(a1, 32, 64);
    a2 += __shfl_xor(a2, 32, 64);
    a3 += __shfl_xor(a3, 32, 64);

    if (lane < 32) {
        float4 b4 = ((const float4*)bias)[l];
        float4 o = make_float4(a0 + b4.x, a1 + b4.y, a2 + b4.z, a3 + b4.w);
        *(float4*)(out + (size_t)node * 128 + l * 4) = o;
    }
}

extern "C" void kernel_launch(void* const* d_in, const int* in_sizes, int n_in,
                              void* d_out, int out_size, void* d_ws, size_t ws_size,
                              hipStream_t stream) {
    const float* x = (const float*)d_in[0];
    const int* row_ptr = (const int*)d_in[1];
    const int* col_ind = (const int*)d_in[2];
    // d_in[3] = max_num_neighbors (row_ptr is authoritative)
    const float* lin_w = (const float*)d_in[4];
    const float* att = (const float*)d_in[5];
    const float* bias = (const float*)d_in[6];
    float* out = (float*)d_out;
    const int n = in_sizes[0] / 128;

    f16* xp = (f16*)d_ws;                                          // n*128 f16
    float* a_src = (float*)((char*)d_ws + (size_t)n * 128 * 2);    // n*4 f32
    float* a_dst = a_src + (size_t)n * HEADS;                      // n*4 f32
    f16* wt = (f16*)(a_dst + (size_t)n * HEADS);                   // 128*128 f16

    hipLaunchKernelGGL(wt_kernel, dim3(8), dim3(256), 0, stream, lin_w, wt);
    hipLaunchKernelGGL(gat_proj_mfma, dim3((n + MB - 1) / MB), dim3(256), 0, stream,
                       x, wt, att, xp, a_src, a_dst, n);
    hipLaunchKernelGGL(gat_aggr_kernel, dim3((n + 3) / 4), dim3(256), 0, stream,
                       xp, a_src, a_dst, row_ptr, col_ind, bias, out, n);
}

// Round 4
// 71.321 us; speedup vs baseline: 2.4435x; 1.0743x over previous
//
#include <hip/hip_runtime.h>
#include <stdint.h>

#define HEADS 4
#define NEG_SLOPE 0.2f
#define MB 64      // rows per block in projection kernel

typedef _Float16 f16;
typedef f16 f16x8 __attribute__((ext_vector_type(8)));
typedef f16 f16x4 __attribute__((ext_vector_type(4)));
typedef float f32x4 __attribute__((ext_vector_type(4)));

// swizzled LDS byte offset for a [rows][128] f16 tile (256 B rows):
// XOR row bits into the 16B-slot bits to kill the 16-way bank conflict
#define SWZ(row, kb) (((row) << 8) + ((kb) ^ (((row) & 7) << 4)))

// ---- pre-kernel: w (f32 [K=128][N=128]) -> wt (f16 [N=128][K=128]) ----
__global__ __launch_bounds__(256) void wt_kernel(const float* __restrict__ w,
                                                 f16* __restrict__ wt) {
    __shared__ f16 tl[16][136];  // +8 pad
    const int b = blockIdx.x, t = threadIdx.x;
    for (int i = t; i < 2048; i += 256) {   // 128 k-rows x 16 cols of this slice
        int k = i >> 4, nl = i & 15;
        tl[nl][k] = (f16)w[k * 128 + b * 16 + nl];
    }
    __syncthreads();
    {
        int nl = t >> 4, kc = t & 15;       // 16 rows x 16 chunks = 256 threads
        f16x8 v = *(const f16x8*)&tl[nl][kc * 8];
        *(f16x8*)(wt + (b * 16 + nl) * 128 + kc * 8) = v;
    }
}

// ---- projection: xp = f16(x) @ f16(w) via MFMA, + logit dots a_src/a_dst ----
__global__ __launch_bounds__(256) void gat_proj_mfma(
    const float* __restrict__ x, const f16* __restrict__ wt,
    const float* __restrict__ att, f16* __restrict__ xp,
    float* __restrict__ a_src, float* __restrict__ a_dst, int n) {
    __shared__ unsigned char lds[49152];   // [0,32K) = wt swizzled; [32K,48K) = x / xp swizzled
    __shared__ float att_l[256];
    const int t = threadIdx.x;
    const int node0 = blockIdx.x * MB;
    const int lane = t & 63;
    const int wv = t >> 6;

    att_l[t] = att[t];

    // stage wt (f16, already [N][K]) into swizzled LDS
    for (int i = t; i < 2048; i += 256) {
        int row = i >> 4, kc = i & 15;
        uint4 v = *(const uint4*)(wt + row * 128 + kc * 8);
        *(uint4*)(lds + SWZ(row, kc * 16)) = v;
    }
    // stage x tile (MB=64 rows), converting f32 -> f16
    for (int i = t; i < 1024; i += 256) {
        int row = i >> 4, kc = i & 15;
        int grow = node0 + row;
        float4 a = make_float4(0.f, 0.f, 0.f, 0.f), b = a;
        if (grow < n) {
            const float4* p = (const float4*)(x + (size_t)grow * 128 + kc * 8);
            a = p[0];
            b = p[1];
        }
        f16x8 hv;
        hv[0] = (f16)a.x; hv[1] = (f16)a.y; hv[2] = (f16)a.z; hv[3] = (f16)a.w;
        hv[4] = (f16)b.x; hv[5] = (f16)b.y; hv[6] = (f16)b.z; hv[7] = (f16)b.w;
        *(f16x8*)(lds + 32768 + SWZ(row, kc * 16)) = hv;
    }
    __syncthreads();

    // MFMA: wave wv owns rows wv*16 .. wv*16+15 (1 M-frag), all 128 cols
    f32x4 acc[8];
#pragma unroll
    for (int nf = 0; nf < 8; nf++) acc[nf] = (f32x4){0.f, 0.f, 0.f, 0.f};

#pragma unroll
    for (int kt = 0; kt < 4; kt++) {
        const int kb = kt * 64 + (lane >> 4) * 16;
        int arow = wv * 16 + (lane & 15);
        f16x8 afr = *(const f16x8*)(lds + 32768 + SWZ(arow, kb));
#pragma unroll
        for (int nf = 0; nf < 8; nf++) {
            int wrow = nf * 16 + (lane & 15);
            f16x8 bfr = *(const f16x8*)(lds + SWZ(wrow, kb));
            acc[nf] = __builtin_amdgcn_mfma_f32_16x16x32_f16(afr, bfr, acc[nf], 0, 0, 0);
        }
    }

    // repack accumulators (f16) into the x LDS region for vectorized stores
    __syncthreads();  // everyone done reading x LDS
#pragma unroll
    for (int r = 0; r < 4; r++) {
        int row = wv * 16 + (lane >> 4) * 4 + r;
#pragma unroll
        for (int nf = 0; nf < 8; nf++) {
            int col = nf * 16 + (lane & 15);
            *(f16*)(lds + 32768 + SWZ(row, col * 2)) = (f16)acc[nf][r];
        }
    }
    __syncthreads();

    // logit dots: a_src[n,h] = sum_c xp[n,h*32+c]*att[h*32+c]; a_dst with att[128+..]
    {
        int row = t >> 2, h = t & 3;        // 64 rows x 4 heads = 256 threads
        int grow = node0 + row;
        if (grow < n) {
            float s = 0.f, d = 0.f;
#pragma unroll
            for (int cc = 0; cc < 4; cc++) {
                f16x8 v = *(const f16x8*)(lds + 32768 + SWZ(row, h * 64 + cc * 16));
#pragma unroll
                for (int j = 0; j < 8; j++) {
                    float xv = (float)v[j];
                    int c = cc * 8 + j;
                    s = fmaf(xv, att_l[h * 32 + c], s);
                    d = fmaf(xv, att_l[128 + h * 32 + c], d);
                }
            }
            a_src[(size_t)grow * HEADS + h] = s;
            a_dst[(size_t)grow * HEADS + h] = d;
        }
    }
    // write xp tile out (vectorized 16B stores)
    for (int i = t; i < 1024; i += 256) {
        int row = i >> 4, kc = i & 15;
        int grow = node0 + row;
        if (grow < n)
            *(uint4*)(xp + (size_t)grow * 128 + kc * 8) =
                *(const uint4*)(lds + 32768 + SWZ(row, kc * 16));
    }
}

// ---- aggregation: 2 nodes per wave, barrier-free, LDS-free ----
// All loads batched upfront for max memory concurrency:
//   1 row_ptr load (3 entries), 1 col_ind load (16 edges),
//   8 xp-gather instrs (16 rows), 1 a_src gather, 1 a_dst load.
// Softmax: low half = node 0, high half = node 1 (xor 4/8/16 stays in-half).
__global__ __launch_bounds__(256) void gat_aggr_kernel(
    const f16* __restrict__ xp, const float* __restrict__ a_src,
    const float* __restrict__ a_dst, const int* __restrict__ row_ptr,
    const int* __restrict__ col_ind, const float* __restrict__ bias,
    float* __restrict__ out, int n) {
    const int lane = threadIdx.x & 63;
    const int p = lane >> 5, l = lane & 31;
    const int nb = (blockIdx.x * 4 + (threadIdx.x >> 6)) * 2;  // wave's base node
    if (nb >= n) return;

    // row_ptr[nb .. nb+2]
    int rp = 0;
    if (lane < 3) {
        int idx = nb + lane;
        if (idx > n) idx = n;
        rp = row_ptr[idx];
    }
    int rs0 = __shfl(rp, 0, 64), rs1 = __shfl(rp, 1, 64), re1 = __shfl(rp, 2, 64);
    int deg0 = rs1 - rs0, deg1 = re1 - rs1;
    if (deg0 > 8) deg0 = 8;
    if (deg1 > 8) deg1 = 8;
    if (nb + 1 >= n) deg1 = 0;

    // col_ind for 16 edges: lane<16: node j=lane>>3, edge e=lane&7
    int ci = 0;
    if (lane < 16) {
        int j = lane >> 3, e = lane & 7;
        int rs = j ? rs1 : rs0;
        int dg = j ? deg1 : deg0;
        if (e < dg) ci = col_ind[rs + e];
    }

    // 8 xp gathers, all independent & issued back-to-back.
    // instr k: node j=k>>2, edges e=2*(k&3)+p ; 32 lanes x 8B = one 256B row/half
    f16x4 pv[8];
#pragma unroll
    for (int k = 0; k < 8; k++) {
        int j = k >> 2, e = 2 * (k & 3) + p;
        int s = __shfl(ci, j * 8 + e, 64);
        pv[k] = *(const f16x4*)(xp + (size_t)s * 128 + l * 4);
    }

    // softmax: half j handles node nb+j; within half: lane = e*4+h
    const int ea = (l >> 2) & 7, ha = l & 3;
    const int dg = p ? deg1 : deg0;
    int sa = __shfl(ci, p * 8 + ea, 64);
    float v = -1e30f;
    if (ea < dg) {
        float z = a_src[(size_t)sa * HEADS + ha] + a_dst[(size_t)(nb + p) * HEADS + ha];
        v = (z >= 0.f) ? z : NEG_SLOPE * z;
    }
    float m = v;
    m = fmaxf(m, __shfl_xor(m, 4, 64));
    m = fmaxf(m, __shfl_xor(m, 8, 64));
    m = fmaxf(m, __shfl_xor(m, 16, 64));
    float ex = (ea < dg) ? __expf(v - m) : 0.f;
    float ss = ex;
    ss += __shfl_xor(ss, 4, 64);
    ss += __shfl_xor(ss, 8, 64);
    ss += __shfl_xor(ss, 16, 64);
    float alpha = ex * ((ss > 0.f) ? (1.f / ss) : 0.f);

    // accumulate: this lane's 4 cols are head l>>3; half p does edges 2k+p
    const int h = l >> 3;
    float acc[2][4] = {{0.f, 0.f, 0.f, 0.f}, {0.f, 0.f, 0.f, 0.f}};
#pragma unroll
    for (int k = 0; k < 4; k++) {
        int e = 2 * k + p;
#pragma unroll
        for (int j = 0; j < 2; j++) {
            float a = __shfl(alpha, j * 32 + e * 4 + h, 64);
            f16x4 pvv = pv[j * 4 + k];
            acc[j][0] = fmaf(a, (float)pvv[0], acc[j][0]);
            acc[j][1] = fmaf(a, (float)pvv[1], acc[j][1]);
            acc[j][2] = fmaf(a, (float)pvv[2], acc[j][2]);
            acc[j][3] = fmaf(a, (float)pvv[3], acc[j][3]);
        }
    }
#pragma unroll
    for (int j = 0; j < 2; j++)
#pragma unroll
        for (int c = 0; c < 4; c++)
            acc[j][c] += __shfl_xor(acc[j][c], 32, 64);

    // half p stores node nb+p
    if (nb + p < n) {
        float4 b4 = ((const float4*)bias)[l];
        float4 o = make_float4(acc[p][0] + b4.x, acc[p][1] + b4.y,
                               acc[p][2] + b4.z, acc[p][3] + b4.w);
        *(float4*)(out + (size_t)(nb + p) * 128 + l * 4) = o;
    }
}

extern "C" void kernel_launch(void* const* d_in, const int* in_sizes, int n_in,
                              void* d_out, int out_size, void* d_ws, size_t ws_size,
                              hipStream_t stream) {
    const float* x = (const float*)d_in[0];
    const int* row_ptr = (const int*)d_in[1];
    const int* col_ind = (const int*)d_in[2];
    // d_in[3] = max_num_neighbors (row_ptr is authoritative)
    const float* lin_w = (const float*)d_in[4];
    const float* att = (const float*)d_in[5];
    const float* bias = (const float*)d_in[6];
    float* out = (float*)d_out;
    const int n = in_sizes[0] / 128;

    f16* xp = (f16*)d_ws;                                          // n*128 f16
    float* a_src = (float*)((char*)d_ws + (size_t)n * 128 * 2);    // n*4 f32
    float* a_dst = a_src + (size_t)n * HEADS;                      // n*4 f32
    f16* wt = (f16*)(a_dst + (size_t)n * HEADS);                   // 128*128 f16

    hipLaunchKernelGGL(wt_kernel, dim3(8), dim3(256), 0, stream, lin_w, wt);
    hipLaunchKernelGGL(gat_proj_mfma, dim3((n + MB - 1) / MB), dim3(256), 0, stream,
                       x, wt, att, xp, a_src, a_dst, n);
    hipLaunchKernelGGL(gat_aggr_kernel, dim3((n + 7) / 8), dim3(256), 0, stream,
                       xp, a_src, a_dst, row_ptr, col_ind, bias, out, n);
}

// Round 5
// 69.423 us; speedup vs baseline: 2.5102x; 1.0273x over previous
//
#include <hip/hip_runtime.h>
#include <stdint.h>

#define HEADS 4
#define NEG_SLOPE 0.2f
#define MB 64      // rows per block in projection kernel

typedef _Float16 f16;
typedef f16 f16x8 __attribute__((ext_vector_type(8)));
typedef f16 f16x4 __attribute__((ext_vector_type(4)));
typedef float f32x4 __attribute__((ext_vector_type(4)));
typedef unsigned int u32x4 __attribute__((ext_vector_type(4)));

// swizzled LDS byte offset for a [rows][128] f16 tile (256 B rows):
// XOR row bits into the 16B-slot bits to kill the 16-way bank conflict
#define SWZ(row, kb) (((row) << 8) + ((kb) ^ (((row) & 7) << 4)))

// ---- pre-kernel: w (f32 [K=128][N=128]) -> wt (f16 [N=128][K=128]) ----
__global__ __launch_bounds__(256) void wt_kernel(const float* __restrict__ w,
                                                 f16* __restrict__ wt) {
    __shared__ f16 tl[16][136];  // +8 pad
    const int b = blockIdx.x, t = threadIdx.x;
    for (int i = t; i < 2048; i += 256) {   // 128 k-rows x 16 cols of this slice
        int k = i >> 4, nl = i & 15;
        tl[nl][k] = (f16)w[k * 128 + b * 16 + nl];
    }
    __syncthreads();
    {
        int nl = t >> 4, kc = t & 15;       // 16 rows x 16 chunks = 256 threads
        f16x8 v = *(const f16x8*)&tl[nl][kc * 8];
        *(f16x8*)(wt + (b * 16 + nl) * 128 + kc * 8) = v;
    }
}

// ---- projection: xp = f16(x) @ f16(w) via MFMA, + logit dots a_src/a_dst ----
// A-fragments loaded straight from global (no x LDS staging); LDS holds only
// wt (32 KB, swizzled) and is reused for the xp repack after the MFMA loop.
__global__ __launch_bounds__(256) void gat_proj_mfma(
    const float* __restrict__ x, const f16* __restrict__ wt,
    const float* __restrict__ att, f16* __restrict__ xp,
    float* __restrict__ a_src, float* __restrict__ a_dst, int n) {
    __shared__ unsigned char lds[32768];
    __shared__ float att_l[256];
    const int t = threadIdx.x;
    const int node0 = blockIdx.x * MB;
    const int lane = t & 63;
    const int wv = t >> 6;

    att_l[t] = att[t];

    // A-frags: row = node0 + wv*16 + (lane&15); kt-frag covers cols kt*32+(lane>>4)*8..+8
    const int arow = node0 + wv * 16 + (lane & 15);
    const bool rowok = arow < n;
    const float* xr = x + (size_t)arow * 128 + (lane >> 4) * 8;
    f16x8 afr[4];
#pragma unroll
    for (int kt = 0; kt < 4; kt++) {
        float4 a = make_float4(0.f, 0.f, 0.f, 0.f), b = a;
        if (rowok) {
            a = *(const float4*)(xr + kt * 32);
            b = *(const float4*)(xr + kt * 32 + 4);
        }
        f16x8 hv;
        hv[0] = (f16)a.x; hv[1] = (f16)a.y; hv[2] = (f16)a.z; hv[3] = (f16)a.w;
        hv[4] = (f16)b.x; hv[5] = (f16)b.y; hv[6] = (f16)b.z; hv[7] = (f16)b.w;
        afr[kt] = hv;
    }

    // stage wt (f16, [N][K]) into swizzled LDS
    for (int i = t; i < 2048; i += 256) {
        int row = i >> 4, kc = i & 15;
        uint4 v = *(const uint4*)(wt + row * 128 + kc * 8);
        *(uint4*)(lds + SWZ(row, kc * 16)) = v;
    }
    __syncthreads();

    // MFMA: wave wv owns rows wv*16..+15 (1 M-frag), all 128 cols
    f32x4 acc[8];
#pragma unroll
    for (int nf = 0; nf < 8; nf++) acc[nf] = (f32x4){0.f, 0.f, 0.f, 0.f};

#pragma unroll
    for (int kt = 0; kt < 4; kt++) {
        const int kb = kt * 64 + (lane >> 4) * 16;
#pragma unroll
        for (int nf = 0; nf < 8; nf++) {
            f16x8 bfr = *(const f16x8*)(lds + SWZ(nf * 16 + (lane & 15), kb));
            acc[nf] = __builtin_amdgcn_mfma_f32_16x16x32_f16(afr[kt], bfr, acc[nf], 0, 0, 0);
        }
    }

    // repack accumulators (f16) into the (now-free) wt LDS region
    __syncthreads();  // all wt reads done
#pragma unroll
    for (int r = 0; r < 4; r++) {
        int row = wv * 16 + (lane >> 4) * 4 + r;
#pragma unroll
        for (int nf = 0; nf < 8; nf++) {
            int col = nf * 16 + (lane & 15);
            *(f16*)(lds + SWZ(row, col * 2)) = (f16)acc[nf][r];
        }
    }
    __syncthreads();

    // logit dots: a_src[n,h] = sum_c xp[n,h*32+c]*att[h*32+c]; a_dst with att[128+..]
    {
        int row = t >> 2, h = t & 3;        // 64 rows x 4 heads = 256 threads
        int grow = node0 + row;
        if (grow < n) {
            float s = 0.f, d = 0.f;
#pragma unroll
            for (int cc = 0; cc < 4; cc++) {
                f16x8 v = *(const f16x8*)(lds + SWZ(row, h * 64 + cc * 16));
#pragma unroll
                for (int j = 0; j < 8; j++) {
                    float xv = (float)v[j];
                    int c = cc * 8 + j;
                    s = fmaf(xv, att_l[h * 32 + c], s);
                    d = fmaf(xv, att_l[128 + h * 32 + c], d);
                }
            }
            a_src[(size_t)grow * HEADS + h] = s;
            a_dst[(size_t)grow * HEADS + h] = d;
        }
    }
    // write xp tile out (vectorized, non-temporal: consumed by a later kernel)
    for (int i = t; i < 1024; i += 256) {
        int row = i >> 4, kc = i & 15;
        int grow = node0 + row;
        if (grow < n) {
            u32x4 v = *(const u32x4*)(lds + SWZ(row, kc * 16));
            __builtin_nontemporal_store(v, (u32x4*)(xp + (size_t)grow * 128 + kc * 8));
        }
    }
}

// ---- aggregation: 4 nodes per wave, barrier-free, LDS-free ----
// Serial chain cut to 2 round trips: row_ptr and a SPECULATIVE col_ind load
// (valid iff each node has exactly 8 consecutive edges — verified against
// row_ptr, with a generic cold-path fallback) fly together; then 16 xp-row
// gathers + a_src/a_dst gathers fly together; then softmax/accumulate.
__global__ __launch_bounds__(256) void gat_aggr_kernel(
    const f16* __restrict__ xp, const float* __restrict__ a_src,
    const float* __restrict__ a_dst, const int* __restrict__ row_ptr,
    const int* __restrict__ col_ind, const float* __restrict__ bias,
    float* __restrict__ out, int n, int e_total) {
    const int lane = threadIdx.x & 63;
    const int p = lane >> 5, l = lane & 31;
    const int nb = (blockIdx.x * 4 + (threadIdx.x >> 6)) * 4;  // wave's base node
    if (nb >= n) return;

    // issue row_ptr[nb..nb+4] and speculative col_ind together
    int rp = 0;
    if (lane < 5) {
        int idx = nb + lane;
        if (idx > n) idx = n;
        rp = row_ptr[idx];
    }
    int ci = 0;
    {
        int si = nb * 8 + lane;
        if (lane < 32 && si < e_total) ci = col_ind[si];
    }
    float4 b4 = ((const float4*)bias)[l];

    int rs0 = __shfl(rp, 0, 64), rs1 = __shfl(rp, 1, 64), rs2 = __shfl(rp, 2, 64);
    int rs3 = __shfl(rp, 3, 64), rs4 = __shfl(rp, 4, 64);
    int dg0 = rs1 - rs0, dg1 = rs2 - rs1, dg2 = rs3 - rs2, dg3 = rs4 - rs3;
    if (dg0 > 8) dg0 = 8;
    if (dg1 > 8) dg1 = 8;
    if (dg2 > 8) dg2 = 8;
    if (dg3 > 8) dg3 = 8;
    if (nb + 1 >= n) dg1 = 0;
    if (nb + 2 >= n) dg2 = 0;
    if (nb + 3 >= n) dg3 = 0;
    bool ok = (nb + 4 <= n) && (rs0 == nb * 8) && (rs1 == rs0 + 8) &&
              (rs2 == rs1 + 8) && (rs3 == rs2 + 8) && (rs4 == rs3 + 8);
    if (!ok) {  // cold path: generic per-edge indices (never taken for this graph)
        int j = lane >> 3, e = lane & 7;
        int rsj = (j == 0) ? rs0 : (j == 1) ? rs1 : (j == 2) ? rs2 : rs3;
        int dgj = (j == 0) ? dg0 : (j == 1) ? dg1 : (j == 2) ? dg2 : dg3;
        int v = 0;
        if (lane < 32 && e < dgj) v = col_ind[rsj + e];
        ci = v;
    }

    // 16 xp gathers, back-to-back. instr k: node j=k>>2, edge e=2*(k&3)+p;
    // each: 32 lanes x 8B = one 256B row per half-wave
    f16x4 pv[16];
#pragma unroll
    for (int k = 0; k < 16; k++) {
        int j = k >> 2, e = 2 * (k & 3) + p;
        int s = __shfl(ci, j * 8 + e, 64);
        pv[k] = *(const f16x4*)(xp + (size_t)s * 128 + l * 4);
    }

    // a_src / a_dst gathers for both softmax passes (pass q: half p = node 2q+p)
    const int ea = (l >> 2) & 7, ha = l & 3;
    const int dsel0 = p ? dg1 : dg0;
    const int dsel1 = p ? dg3 : dg2;
    int sa0 = __shfl(ci, (0 * 2 + p) * 8 + ea, 64);
    int sa1 = __shfl(ci, (1 * 2 + p) * 8 + ea, 64);
    float av0 = (ea < dsel0) ? a_src[(size_t)sa0 * HEADS + ha] : 0.f;
    float av1 = (ea < dsel1) ? a_src[(size_t)sa1 * HEADS + ha] : 0.f;
    float dv0 = (nb + p < n) ? a_dst[(size_t)(nb + p) * HEADS + ha] : 0.f;
    float dv1 = (nb + 2 + p < n) ? a_dst[(size_t)(nb + 2 + p) * HEADS + ha] : 0.f;

    // softmax passes (xor 4/8/16 stays within each 32-lane half)
    float alpha[2];
#pragma unroll
    for (int q = 0; q < 2; q++) {
        const int dsel = q ? dsel1 : dsel0;
        float z = (q ? av1 : av0) + (q ? dv1 : dv0);
        float v = (ea < dsel) ? ((z >= 0.f) ? z : NEG_SLOPE * z) : -1e30f;
        float m = v;
        m = fmaxf(m, __shfl_xor(m, 4, 64));
        m = fmaxf(m, __shfl_xor(m, 8, 64));
        m = fmaxf(m, __shfl_xor(m, 16, 64));
        float ex = (ea < dsel) ? __expf(v - m) : 0.f;
        float ss = ex;
        ss += __shfl_xor(ss, 4, 64);
        ss += __shfl_xor(ss, 8, 64);
        ss += __shfl_xor(ss, 16, 64);
        alpha[q] = ex * ((ss > 0.f) ? (1.f / ss) : 0.f);
    }

    // accumulate: this lane's 4 cols are head l>>3; half p does edges 2k+p
    const int h = l >> 3;
    float acc[4][4] = {{0.f, 0.f, 0.f, 0.f}, {0.f, 0.f, 0.f, 0.f},
                       {0.f, 0.f, 0.f, 0.f}, {0.f, 0.f, 0.f, 0.f}};
#pragma unroll
    for (int k = 0; k < 16; k++) {
        const int j = k >> 2;                 // compile-time per unrolled iter
        int e = 2 * (k & 3) + p;
        float a = __shfl(alpha[j >> 1], (j & 1) * 32 + e * 4 + h, 64);
        f16x4 pvv = pv[k];
        acc[j][0] = fmaf(a, (float)pvv[0], acc[j][0]);
        acc[j][1] = fmaf(a, (float)pvv[1], acc[j][1]);
        acc[j][2] = fmaf(a, (float)pvv[2], acc[j][2]);
        acc[j][3] = fmaf(a, (float)pvv[3], acc[j][3]);
    }
#pragma unroll
    for (int j = 0; j < 4; j++)
#pragma unroll
        for (int c = 0; c < 4; c++)
            acc[j][c] += __shfl_xor(acc[j][c], 32, 64);

    // half p stores nodes nb+p and nb+2+p (non-temporal: out is never re-read)
#pragma unroll
    for (int q = 0; q < 2; q++) {
        int j = 2 * q + p;
        if (nb + j < n) {
            f32x4 o;
            o[0] = (p ? acc[2 * q + 1][0] : acc[2 * q][0]) + b4.x;
            o[1] = (p ? acc[2 * q + 1][1] : acc[2 * q][1]) + b4.y;
            o[2] = (p ? acc[2 * q + 1][2] : acc[2 * q][2]) + b4.z;
            o[3] = (p ? acc[2 * q + 1][3] : acc[2 * q][3]) + b4.w;
            __builtin_nontemporal_store(o, (f32x4*)(out + (size_t)(nb + j) * 128 + l * 4));
        }
    }
}

extern "C" void kernel_launch(void* const* d_in, const int* in_sizes, int n_in,
                              void* d_out, int out_size, void* d_ws, size_t ws_size,
                              hipStream_t stream) {
    const float* x = (const float*)d_in[0];
    const int* row_ptr = (const int*)d_in[1];
    const int* col_ind = (const int*)d_in[2];
    // d_in[3] = max_num_neighbors (row_ptr is authoritative)
    const float* lin_w = (const float*)d_in[4];
    const float* att = (const float*)d_in[5];
    const float* bias = (const float*)d_in[6];
    float* out = (float*)d_out;
    const int n = in_sizes[0] / 128;
    const int e_total = in_sizes[2];

    f16* xp = (f16*)d_ws;                                          // n*128 f16
    float* a_src = (float*)((char*)d_ws + (size_t)n * 128 * 2);    // n*4 f32
    float* a_dst = a_src + (size_t)n * HEADS;                      // n*4 f32
    f16* wt = (f16*)(a_dst + (size_t)n * HEADS);                   // 128*128 f16

    hipLaunchKernelGGL(wt_kernel, dim3(8), dim3(256), 0, stream, lin_w, wt);
    hipLaunchKernelGGL(gat_proj_mfma, dim3((n + MB - 1) / MB), dim3(256), 0, stream,
                       x, wt, att, xp, a_src, a_dst, n);
    hipLaunchKernelGGL(gat_aggr_kernel, dim3((n + 15) / 16), dim3(256), 0, stream,
                       xp, a_src, a_dst, row_ptr, col_ind, bias, out, n, e_total);
}